// Round 6
// baseline (241.561 us; speedup 1.0000x reference)
//
#include <hip/hip_runtime.h>
#include <math.h>

// DivEncoder: x[N,H] -> per-group (D=512 groups, V=16) conv to U=64, ELU,
// conv U->1, row-wise L2 normalize. All fp32 in/out.
#define D_ 512
#define H_ 8192
#define U_ 64
#define V_ 16
#define N_ 4096
#define DUV (D_ * U_ * V_)     // 524288
#define DU  (D_ * U_)          // 32768

#define LOG2E 1.4426950408889634f
#define LN2   0.6931471805599453f

// Block geometry: 64 rows x 8 groups, 256 threads (4 waves).
// Wave w handles groups {2w, 2w+1}, 4 row-tiles of 16 rows each.
#define BR 64
#define BG 8
#define XSTR 136   // bf16 row stride (272 B): 16B-aligned rows, 2-way banks only
#define YSTR 12    // f32 row stride (48 B): 16B-aligned

typedef __bf16 bf16x8 __attribute__((ext_vector_type(8)));
typedef __bf16 bf16x4 __attribute__((ext_vector_type(4)));
typedef float f32x4 __attribute__((ext_vector_type(4)));

// ws layout: apack bf16[DUV*2... actually D*4*64*8] @0 (1 MB) | b1s f32[DU] | w2s f32[DU]
#define APACK_ELEMS (D_ * 4 * 64 * 8)   // 1,048,576 bf16 = 2 MB? no: = DUV*2 = 1M elems, 2 MB
#define WS_NEEDED (APACK_ELEMS * sizeof(__bf16) + 2 * DU * sizeof(float))

// Prep A: pack W1*log2e into MFMA A-fragment order, split-precision in K:
// A[m][k<16] = hi(w*log2e), A[m][k>=16] = lo. Lane (q=lane>>4, m=lane&15)
// holds 8 bf16 at apack[((d*4+c)*64+lane)*8]: q0/q1 = hi v[0..7]/v[8..15],
// q2/q3 = lo same. One MFMA then computes (w_hi+w_lo)*x = w*x exact in w.
__global__ __launch_bounds__(256) void k0_pack_w1(const float* __restrict__ W1,
                                                  __bf16* __restrict__ apack) {
    const int idx  = blockIdx.x * 256 + threadIdx.x;   // [0, D*4*64)
    const int lane = idx & 63;
    const int c    = (idx >> 6) & 3;
    const int d    = idx >> 8;
    const int q    = lane >> 4;
    const int m    = lane & 15;
    const int vb   = (q & 1) * 8;

    const float* src = W1 + ((size_t)d * U_ + c * 16 + m) * V_ + vb;
    f32x4 w0 = *(const f32x4*)src;
    f32x4 w1 = *(const f32x4*)(src + 4);
    float wf[8] = {w0.x, w0.y, w0.z, w0.w, w1.x, w1.y, w1.z, w1.w};
    bf16x8 out;
    #pragma unroll
    for (int j = 0; j < 8; ++j) {
        float ws_ = wf[j] * LOG2E;
        __bf16 hi = (__bf16)ws_;
        out[j] = (q < 2) ? hi : (__bf16)(ws_ - (float)hi);
    }
    *(bf16x8*)(apack + (size_t)idx * 8) = out;
}

// Prep B: b1 * log2e, W2 * ln2 (fp32).
__global__ __launch_bounds__(256) void k0_scale_b1w2(const float* __restrict__ b1,
                                                     const float* __restrict__ W2,
                                                     float* __restrict__ b1s,
                                                     float* __restrict__ w2s) {
    const int i4 = (blockIdx.x * 256 + threadIdx.x) * 4;
    f32x4 b = *(const f32x4*)(b1 + i4);
    f32x4 w = *(const f32x4*)(W2 + i4);
    #pragma unroll
    for (int j = 0; j < 4; ++j) { b[j] *= LOG2E; w[j] *= LN2; }
    *(f32x4*)(b1s + i4) = b;
    *(f32x4*)(w2s + i4) = w;
}

// k1: one mfma_f32_16x16x32_bf16 per (tile, u-chunk): A=[w_hi|w_lo] (packed),
// B=[x_bf16|x_bf16] (replicated via the k=(lane>>4)*8+j layout: v=(q&1)*8+j),
// C preloaded with b1' -> acc = h*log2e. Epilogue in exp2 domain:
//   contribution = (w2*ln2) * max(h', (2^min(h',0) - 1)*log2e) == w2 * elu(h)
// Layouts (HW-verified): A/B: idx=lane&15, k=(lane>>4)*8+j ;
// C/D: col=lane&15, row=(lane>>4)*4+reg.
template <bool PRESPLIT>
__global__ __launch_bounds__(256, 8) void k1_div_encoder(
        const float* __restrict__ x,
        const float* __restrict__ W1,
        const __bf16* __restrict__ apack,
        const float* __restrict__ b1,
        const float* __restrict__ W2,
        const float* __restrict__ b2,
        float* __restrict__ y) {
    __shared__ __bf16 xs[BR][XSTR];      // 17408 B
    __shared__ float  ytile[BR][YSTR];   // 3072 B  -> 20480 total = 8 blocks/CU

    const int tid  = threadIdx.x;
    const int lane = tid & 63;
    const int wave = __builtin_amdgcn_readfirstlane(tid >> 6);
    const int q    = lane >> 4;
    const int m    = lane & 15;
    const int vhalf = (q & 1) * 8;

    // nb fast: 64 consecutive blocks reuse the same ~56 KB weight slice (L2).
    const int nb = blockIdx.x & 63;    // 64 row-blocks
    const int db = blockIdx.x >> 6;    // 64 group-blocks
    const int r0 = nb * BR;
    const int d0 = db * BG;

    // ---- stage 1: coalesced x load, cvt to bf16 -> LDS ----
    {
        const float* xg = x + (size_t)r0 * H_ + (size_t)d0 * V_;
        #pragma unroll
        for (int i = 0; i < 8; ++i) {
            const int flat = tid + i * 256;   // 0..2047
            const int row  = flat >> 5;       // 0..63
            const int c4   = flat & 31;       // f32x4 col
            f32x4 v = *(const f32x4*)(xg + (size_t)row * H_ + c4 * 4);
            bf16x4 h;
            #pragma unroll
            for (int j = 0; j < 4; ++j) h[j] = (__bf16)v[j];
            *(bf16x4*)&xs[row][c4 * 4] = h;
        }
        #pragma unroll
        for (int k = tid; k < BR * YSTR; k += 256) {
            ((float*)ytile)[k] = 0.0f;
        }
    }
    __syncthreads();

    #pragma unroll 1
    for (int gi = 0; gi < 2; ++gi) {
        const int gl = wave * 2 + gi;
        const int d  = d0 + gl;

        bf16x8 Afrag[4];
        f32x4 b1frag[4], w2frag[4];
        if (PRESPLIT) {
            const __bf16* ap = apack + ((size_t)d * 4 * 64 + lane) * 8;
            #pragma unroll
            for (int c = 0; c < 4; ++c) {
                Afrag[c]  = *(const bf16x8*)(ap + c * 512);
                b1frag[c] = *(const f32x4*)(b1 + (size_t)d * U_ + c * 16 + q * 4);
                w2frag[c] = *(const f32x4*)(W2 + (size_t)d * U_ + c * 16 + q * 4);
            }
        } else {
            #pragma unroll
            for (int c = 0; c < 4; ++c) {
                const float* wp = W1 + ((size_t)d * U_ + c * 16 + m) * V_ + vhalf;
                f32x4 w0 = *(const f32x4*)wp;
                f32x4 w1v = *(const f32x4*)(wp + 4);
                float wf[8] = {w0.x, w0.y, w0.z, w0.w, w1v.x, w1v.y, w1v.z, w1v.w};
                bf16x8 a;
                #pragma unroll
                for (int i = 0; i < 8; ++i) {
                    float ws_ = wf[i] * LOG2E;
                    __bf16 h = (__bf16)ws_;
                    a[i] = (q < 2) ? h : (__bf16)(ws_ - (float)h);
                }
                Afrag[c] = a;
                f32x4 bb = *(const f32x4*)(b1 + (size_t)d * U_ + c * 16 + q * 4);
                f32x4 ww = *(const f32x4*)(W2 + (size_t)d * U_ + c * 16 + q * 4);
                #pragma unroll
                for (int j = 0; j < 4; ++j) { bb[j] *= LOG2E; ww[j] *= LN2; }
                b1frag[c] = bb;
                w2frag[c] = ww;
            }
        }

        #pragma unroll 2
        for (int t = 0; t < 4; ++t) {
            bf16x8 bx = *(const bf16x8*)&xs[t * 16 + m][gl * V_ + vhalf];

            float partial = 0.0f;
            #pragma unroll
            for (int c = 0; c < 4; ++c) {
                // C operand = b1frag directly (no acc copy; single MFMA/chunk)
                f32x4 acc = __builtin_amdgcn_mfma_f32_16x16x32_bf16(
                    Afrag[c], bx, b1frag[c], 0, 0, 0);
                #pragma unroll
                for (int r = 0; r < 4; ++r) {
                    float hp = acc[r];                        // h * log2e
                    float mn = fminf(hp, 0.0f);
                    float t2 = __builtin_amdgcn_exp2f(mn);    // e^min(h,0)
                    float e  = fmaf(t2, LOG2E, -LOG2E);       // expm1(h<0)*log2e
                    float vv = fmaxf(hp, e);                  // elu(h)*log2e
                    partial  = fmaf(w2frag[c][r], vv, partial);
                }
            }
            // quads hold disjoint u-subsets of the row's dot -> LDS atomic
            atomicAdd(&ytile[t * 16 + m][gl], partial);
        }
    }
    __syncthreads();

    // ---- stage 3: + b2, coalesced y store ----
    if (tid < 128) {
        const int row  = tid >> 1;
        const int half = tid & 1;
        f32x4 v  = *(const f32x4*)&ytile[row][half * 4];
        f32x4 bb = *(const f32x4*)(b2 + d0 + half * 4);
        #pragma unroll
        for (int j = 0; j < 4; ++j) v[j] += bb[j];
        *(f32x4*)(y + (size_t)(r0 + row) * D_ + d0 + half * 4) = v;
    }
}

// Kernel 2: row-wise L2 normalize in place. One block (256 threads) per row.
__global__ __launch_bounds__(256) void k2_l2_normalize(float* __restrict__ y) {
    const int n = blockIdx.x;
    const int t = threadIdx.x;
    float* row = y + (size_t)n * D_;

    float v0 = row[t];
    float v1 = row[t + 256];
    float ss = v0 * v0 + v1 * v1;

    #pragma unroll
    for (int off = 32; off > 0; off >>= 1) {
        ss += __shfl_down(ss, off, 64);
    }

    __shared__ float wsum[4];
    if ((t & 63) == 0) wsum[t >> 6] = ss;
    __syncthreads();
    const float tot = wsum[0] + wsum[1] + wsum[2] + wsum[3];

    const float scale = 1.0f / fmaxf(sqrtf(tot), 1e-12f);

    row[t]       = v0 * scale;
    row[t + 256] = v1 * scale;
}

extern "C" void kernel_launch(void* const* d_in, const int* in_sizes, int n_in,
                              void* d_out, int out_size, void* d_ws, size_t ws_size,
                              hipStream_t stream) {
    const float* x  = (const float*)d_in[0];
    const float* W1 = (const float*)d_in[1];
    const float* b1 = (const float*)d_in[2];
    const float* W2 = (const float*)d_in[3];
    const float* b2 = (const float*)d_in[4];
    float* y = (float*)d_out;  // [N, D] fp32

    const dim3 grid((N_ / BR) * (D_ / BG));
    if (ws_size >= WS_NEEDED) {
        __bf16* apack = (__bf16*)d_ws;
        float* b1s = (float*)((char*)d_ws + APACK_ELEMS * sizeof(__bf16));
        float* w2s = b1s + DU;
        k0_pack_w1<<<dim3(D_ * 4 * 64 / 256), dim3(256), 0, stream>>>(W1, apack);
        k0_scale_b1w2<<<dim3(DU / 4 / 256), dim3(256), 0, stream>>>(b1, W2, b1s, w2s);
        k1_div_encoder<true><<<grid, dim3(256), 0, stream>>>(
            x, W1, apack, b1s, w2s, b2, y);
    } else {
        k1_div_encoder<false><<<grid, dim3(256), 0, stream>>>(
            x, W1, (const __bf16*)nullptr, b1, W2, b2, y);
    }
    k2_l2_normalize<<<dim3(N_), dim3(256), 0, stream>>>(y);
}